// Round 2
// baseline (18868.663 us; speedup 1.0000x reference)
//
#include <hip/hip_runtime.h>
#include <hip/hip_bf16.h>
#include <math.h>

typedef __bf16 bf16;
typedef __bf16 bf16x8 __attribute__((ext_vector_type(8)));
typedef __bf16 bf16x4 __attribute__((ext_vector_type(4)));
typedef float f32x4 __attribute__((ext_vector_type(4)));

#define T_LEN 512
#define BATCH 64
#define HDIM  1024
#define IDIM  512

struct Ptr12 { const float* p[12]; };
struct Ptr6  { const float* p[6];  };

// ---------------------------------------------------------------------------
// K0: transpose + fp32->bf16 convert all weight matrices.
// z 0..5  : W_h (K=1024): hr_f, hz_f, hh_f, hr_b, hz_b, hh_b  -> wt_h [n][k]
// z 6..11 : W_x (K=512):  xr_f, xz_f, xh_f, xr_b, xz_b, xh_b  -> wt_x [n][k]
// ---------------------------------------------------------------------------
__global__ __launch_bounds__(256) void transpose_convert(Ptr12 W, bf16* wt_h, bf16* wt_x) {
    int z = blockIdx.z;
    int K = (z < 6) ? HDIM : IDIM;
    const float* src = W.p[z];
    bf16* dst = (z < 6) ? (wt_h + (size_t)z * HDIM * HDIM)
                        : (wt_x + (size_t)(z - 6) * HDIM * IDIM);
    int n0 = blockIdx.x * 32;
    int k0 = blockIdx.y * 32;
    if (k0 >= K) return;
    __shared__ float tile[32][33];
    int tx = threadIdx.x & 31, ty = threadIdx.x >> 5;
#pragma unroll
    for (int i = 0; i < 32; i += 8)
        tile[ty + i][tx] = src[(size_t)(k0 + ty + i) * HDIM + n0 + tx];
    __syncthreads();
#pragma unroll
    for (int i = 0; i < 32; i += 8)
        dst[(size_t)(n0 + ty + i) * K + k0 + tx] = (bf16)tile[tx][ty + i];
}

// ---------------------------------------------------------------------------
// K0b: x fp32 -> bf16
// ---------------------------------------------------------------------------
__global__ __launch_bounds__(256) void convert_x(const float* __restrict__ x, bf16* __restrict__ xbf) {
    size_t i = ((size_t)blockIdx.x * blockDim.x + threadIdx.x) * 4;
    float4 v = *(const float4*)(x + i);
    bf16x4 o = { (bf16)v.x, (bf16)v.y, (bf16)v.z, (bf16)v.w };
    *(bf16x4*)(xbf + i) = o;
}

// ---------------------------------------------------------------------------
// K0c: init h state (bf16) + zero barrier counters
// ---------------------------------------------------------------------------
__global__ __launch_bounds__(256) void init_h(const float* __restrict__ hf, const float* __restrict__ hb,
                                              bf16* __restrict__ h_cur, unsigned* __restrict__ bars) {
    int i = blockIdx.x * blockDim.x + threadIdx.x;
    h_cur[i] = (bf16)hf[i];
    h_cur[BATCH * HDIM + i] = (bf16)hb[i];
    if (blockIdx.x == 0) bars[threadIdx.x] = 0u;   // 256 u32 covers all 4 group counters
}

// ---------------------------------------------------------------------------
// K1: xproj GEMM. XP[g][t][b][n] = (x @ W_x_g)[b*T+t][n] + bias_g[n], bf16.
// ---------------------------------------------------------------------------
__global__ __launch_bounds__(256) void xproj_gemm(const bf16* __restrict__ xbf,
                                                  const bf16* __restrict__ wt_x,
                                                  Ptr6 biases,
                                                  bf16* __restrict__ XP) {
    int g  = blockIdx.z;
    int m0 = blockIdx.x * 64;
    int n0 = blockIdx.y * 64;
    int w  = threadIdx.x >> 6;
    int l  = threadIdx.x & 63;
    int lm = l & 15, lq = l >> 4;

    const bf16* Wg    = wt_x + (size_t)g * HDIM * IDIM;
    const bf16* Abase = xbf + (size_t)(m0 + 16 * w + lm) * IDIM + lq * 8;
    const bf16* Bbase = Wg + (size_t)(n0 + lm) * IDIM + lq * 8;

    f32x4 acc[4] = {};
#pragma unroll 2
    for (int k = 0; k < IDIM; k += 32) {
        bf16x8 a = *(const bf16x8*)(Abase + k);
#pragma unroll
        for (int nt = 0; nt < 4; nt++) {
            bf16x8 b = *(const bf16x8*)(Bbase + (size_t)nt * 16 * IDIM + k);
            acc[nt] = __builtin_amdgcn_mfma_f32_16x16x32_bf16(a, b, acc[nt], 0, 0, 0);
        }
    }

    const float* bias = biases.p[g];
    int mrow = m0 + 16 * w + lq * 4;
#pragma unroll
    for (int nt = 0; nt < 4; nt++) {
        int n = n0 + nt * 16 + lm;
        float bv = bias[n];
#pragma unroll
        for (int r = 0; r < 4; r++) {
            int m = mrow + r;
            int b_ = m >> 9;
            int t  = m & 511;
            XP[(((size_t)g * T_LEN + t) * BATCH + b_) * HDIM + n] = (bf16)(acc[nt][r] + bv);
        }
    }
}

// ---------------------------------------------------------------------------
// Group barrier over 64 blocks (one (dir,gb) group). Monotonic counter; no
// sense reversal needed. fetch_add(ACQ_REL) releases this block's stores;
// the ACQUIRE spin-load synchronizes with every other block's release.
// ---------------------------------------------------------------------------
__device__ inline void group_barrier(unsigned* ctr, unsigned target) {
    __syncthreads();
    if (threadIdx.x == 0) {
        __hip_atomic_fetch_add(ctr, 1u, __ATOMIC_ACQ_REL, __HIP_MEMORY_SCOPE_AGENT);
        while (__hip_atomic_load(ctr, __ATOMIC_ACQUIRE, __HIP_MEMORY_SCOPE_AGENT) < target) { }
    }
    __syncthreads();
}

// ---------------------------------------------------------------------------
// K2: persistent recurrence kernel (cooperative launch, 256 blocks x 256 thr).
// block = (dir, gb batch-half, s 16-col slice). Weights for the block's 16
// columns (3 gates x K=1024 = 96 KB) pinned in LDS for all 512 steps.
// Per step: phase A (4 waves = 2 gates x 2 row-tiles): R,Z; Rh->global,
// Z->LDS. group barrier. phase B (4 waves = 2 row-tiles x 2 K-halves):
// (R*h)@W_hh with LDS reduce; tanh; h update; out write. group barrier.
// LDS weight layout: [gate][k>>3][col][8 elems] -> wave B-fragment read is
// 1024 contiguous bytes (conflict-free).
// ---------------------------------------------------------------------------
__global__ __launch_bounds__(256, 1) void gru_persistent(
        const bf16* __restrict__ wt_h, const bf16* __restrict__ XP,
        bf16* __restrict__ h_cur, bf16* __restrict__ Rh,
        float* __restrict__ out, unsigned* __restrict__ bars)
{
    __shared__ __align__(16) char  Wl[98304];   // 3 gates x 32768 B
    __shared__ __align__(16) float Part[512];   // phase-B cross-wave partials
    __shared__ __align__(16) float Zs[512];     // Z gate, phase A -> phase B

    const int blk = blockIdx.x;
    const int dir = blk >> 7;
    const int gb  = (blk >> 6) & 1;
    const int s   = blk & 63;
    const int n0  = s * 16;
    const int tid = threadIdx.x;
    const int w   = tid >> 6, l = tid & 63;
    const int lm  = l & 15, lq = l >> 4;

    // ---- preload this block's weight slices into LDS
    for (int gate = 0; gate < 3; ++gate) {
        const bf16* Wg = wt_h + ((size_t)(dir * 3 + gate) * HDIM + n0) * HDIM;
        char* dst = Wl + gate * 32768;
        for (int idx = tid; idx < 2048; idx += 256) {
            int c = idx & 15, kb = idx >> 4;           // col, 16B-chunk index
            bf16x8 v = *(const bf16x8*)(Wg + (size_t)c * HDIM + kb * 8);
            *(bf16x8*)(dst + kb * 256 + c * 16) = v;   // contiguous LDS write per 16 lanes
        }
    }
    __syncthreads();

    bf16* h_d  = h_cur + (size_t)dir * BATCH * HDIM;
    bf16* Rh_d = Rh    + (size_t)dir * BATCH * HDIM;
    unsigned* ctr = bars + (dir * 2 + gb) * 64;        // 256B-spaced counters

    const int gate = w >> 1;                 // phase A: 0=R, 1=Z
    const int mt   = w & 1;                  // row tile (both phases)
    const int kh   = w >> 1;                 // phase B: K-half
    const int rowA = gb * 32 + mt * 16 + lm; // A-fragment row
    const int brow = gb * 32 + mt * 16 + lq * 4;
    const int n    = n0 + lm;

    const char* BlA = Wl + gate * 32768 + lq * 256 + lm * 16;
    const char* BlB = Wl + 2 * 32768 + kh * 16384 + lq * 256 + lm * 16;

    unsigned bt = 0;

#pragma unroll 1
    for (int step = 0; step < T_LEN; ++step) {
        const int t = dir ? (T_LEN - 1 - step) : step;

        // ======================= phase A: R / Z =======================
        {
            const bf16* A   = h_d + (size_t)rowA * HDIM + lq * 8;
            const bf16* xpA = XP + ((size_t)(dir * 3 + gate) * T_LEN + t) * BATCH * HDIM;
            float xpv[4], hvv[4] = {};
#pragma unroll
            for (int r = 0; r < 4; ++r)
                xpv[r] = (float)xpA[(size_t)(brow + r) * HDIM + n];
            if (gate == 0) {
#pragma unroll
                for (int r = 0; r < 4; ++r)
                    hvv[r] = (float)h_d[(size_t)(brow + r) * HDIM + n];
            }
            bf16x8 a[32];
#pragma unroll
            for (int i = 0; i < 32; ++i)
                a[i] = *(const bf16x8*)(A + i * 32);
            f32x4 acc0 = {}, acc1 = {};
#pragma unroll
            for (int i = 0; i < 32; i += 2) {
                bf16x8 b0 = *(const bf16x8*)(BlA + i * 1024);
                acc0 = __builtin_amdgcn_mfma_f32_16x16x32_bf16(a[i], b0, acc0, 0, 0, 0);
                bf16x8 b1 = *(const bf16x8*)(BlA + i * 1024 + 1024);
                acc1 = __builtin_amdgcn_mfma_f32_16x16x32_bf16(a[i + 1], b1, acc1, 0, 0, 0);
            }
            f32x4 acc = acc0 + acc1;
#pragma unroll
            for (int r = 0; r < 4; ++r) {
                float pre = acc[r] + xpv[r];
                float gv = 1.0f / (1.0f + __expf(-pre));
                if (gate == 0) {
                    Rh_d[(size_t)(brow + r) * HDIM + n] = (bf16)(gv * hvv[r]);
                } else {
                    Zs[mt * 256 + l * 4 + r] = gv;
                }
            }
        }
        bt += 64; group_barrier(ctr, bt);

        // =================== phase B: h_til & update ===================
        {
            const bf16* A = Rh_d + (size_t)rowA * HDIM + kh * 512 + lq * 8;
            bf16x8 a[16];
#pragma unroll
            for (int i = 0; i < 16; ++i)
                a[i] = *(const bf16x8*)(A + i * 32);
            f32x4 acc0 = {}, acc1 = {};
#pragma unroll
            for (int i = 0; i < 16; i += 2) {
                bf16x8 b0 = *(const bf16x8*)(BlB + i * 1024);
                acc0 = __builtin_amdgcn_mfma_f32_16x16x32_bf16(a[i], b0, acc0, 0, 0, 0);
                bf16x8 b1 = *(const bf16x8*)(BlB + i * 1024 + 1024);
                acc1 = __builtin_amdgcn_mfma_f32_16x16x32_bf16(a[i + 1], b1, acc1, 0, 0, 0);
            }
            f32x4 p = acc0 + acc1;
            if (kh == 1)
                *(f32x4*)(&Part[mt * 256 + l * 4]) = p;
            __syncthreads();
            if (kh == 0) {
                const bf16* xpH = XP + ((size_t)(dir * 3 + 2) * T_LEN + t) * BATCH * HDIM;
                f32x4 q = *(const f32x4*)(&Part[mt * 256 + l * 4]);
#pragma unroll
                for (int r = 0; r < 4; ++r) {
                    int b_ = brow + r;
                    float pre = p[r] + q[r] + (float)xpH[(size_t)b_ * HDIM + n];
                    float e2x = __expf(2.0f * pre);
                    float ht  = (e2x - 1.0f) / (e2x + 1.0f);
                    float z   = Zs[mt * 256 + l * 4 + r];
                    float ho  = (float)h_d[(size_t)b_ * HDIM + n];
                    float hn  = z * ht + (1.0f - z) * ho;
                    h_d[(size_t)b_ * HDIM + n] = (bf16)hn;
                    out[((size_t)b_ * T_LEN + t) * (2 * HDIM) + (size_t)dir * HDIM + n] = hn;
                }
            }
        }
        bt += 64; group_barrier(ctr, bt);
    }
}

// ---------------------------------------------------------------------------
extern "C" void kernel_launch(void* const* d_in, const int* in_sizes, int n_in,
                              void* d_out, int out_size, void* d_ws, size_t ws_size,
                              hipStream_t stream) {
    const float* x   = (const float*)d_in[0];
    const float* hpf = (const float*)d_in[1];
    const float* hpb = (const float*)d_in[2];

    unsigned char* ws = (unsigned char*)d_ws;
    size_t off = 0;
    bf16* wt_h = (bf16*)(ws + off); off += (size_t)6 * HDIM * HDIM * 2;
    bf16* wt_x = (bf16*)(ws + off); off += (size_t)6 * HDIM * IDIM * 2;
    bf16* xbf  = (bf16*)(ws + off); off += (size_t)BATCH * T_LEN * IDIM * 2;
    bf16* XP   = (bf16*)(ws + off); off += (size_t)6 * T_LEN * BATCH * HDIM * 2;
    bf16* h_cur = (bf16*)(ws + off); off += (size_t)2 * BATCH * HDIM * 2;
    bf16* Rh    = (bf16*)(ws + off); off += (size_t)2 * BATCH * HDIM * 2;
    unsigned* bars = (unsigned*)(ws + off); off += 1024;   // 4 counters, 256B apart

    float* out = (float*)d_out;

    Ptr12 wp;
    wp.p[0] = (const float*)d_in[3];  wp.p[1] = (const float*)d_in[6];  wp.p[2] = (const float*)d_in[9];
    wp.p[3] = (const float*)d_in[12]; wp.p[4] = (const float*)d_in[15]; wp.p[5] = (const float*)d_in[18];
    wp.p[6] = (const float*)d_in[4];  wp.p[7] = (const float*)d_in[7];  wp.p[8] = (const float*)d_in[10];
    wp.p[9] = (const float*)d_in[13]; wp.p[10] = (const float*)d_in[16]; wp.p[11] = (const float*)d_in[19];
    transpose_convert<<<dim3(32, 32, 12), 256, 0, stream>>>(wp, wt_h, wt_x);

    convert_x<<<16384, 256, 0, stream>>>(x, xbf);
    init_h<<<256, 256, 0, stream>>>(hpf, hpb, h_cur, bars);

    Ptr6 bp;
    bp.p[0] = (const float*)d_in[5];  bp.p[1] = (const float*)d_in[8];  bp.p[2] = (const float*)d_in[11];
    bp.p[3] = (const float*)d_in[14]; bp.p[4] = (const float*)d_in[17]; bp.p[5] = (const float*)d_in[20];
    xproj_gemm<<<dim3(512, 16, 6), 256, 0, stream>>>(xbf, wt_x, bp, XP);

    // Persistent recurrence: one cooperative kernel, 512 steps inside.
    void* args[] = { (void*)&wt_h, (void*)&XP, (void*)&h_cur, (void*)&Rh,
                     (void*)&out, (void*)&bars };
    (void)hipLaunchCooperativeKernel((void*)gru_persistent, dim3(256), dim3(256), args, 0, stream);
}

// Round 3
// 16377.736 us; speedup vs baseline: 1.1521x; 1.1521x over previous
//
#include <hip/hip_runtime.h>
#include <hip/hip_bf16.h>
#include <math.h>

typedef __bf16 bf16;
typedef __bf16 bf16x8 __attribute__((ext_vector_type(8)));
typedef __bf16 bf16x4 __attribute__((ext_vector_type(4)));
typedef float f32x4 __attribute__((ext_vector_type(4)));

#define T_LEN 512
#define BATCH 64
#define HDIM  1024
#define IDIM  512

struct Ptr12 { const float* p[12]; };
struct Ptr6  { const float* p[6];  };

// ---------------------------------------------------------------------------
// K0: transpose + fp32->bf16 convert all weight matrices.
// z 0..5  : W_h (K=1024): hr_f, hz_f, hh_f, hr_b, hz_b, hh_b  -> wt_h [n][k]
// z 6..11 : W_x (K=512):  xr_f, xz_f, xh_f, xr_b, xz_b, xh_b  -> wt_x [n][k]
// ---------------------------------------------------------------------------
__global__ __launch_bounds__(256) void transpose_convert(Ptr12 W, bf16* wt_h, bf16* wt_x) {
    int z = blockIdx.z;
    int K = (z < 6) ? HDIM : IDIM;
    const float* src = W.p[z];
    bf16* dst = (z < 6) ? (wt_h + (size_t)z * HDIM * HDIM)
                        : (wt_x + (size_t)(z - 6) * HDIM * IDIM);
    int n0 = blockIdx.x * 32;
    int k0 = blockIdx.y * 32;
    if (k0 >= K) return;
    __shared__ float tile[32][33];
    int tx = threadIdx.x & 31, ty = threadIdx.x >> 5;
#pragma unroll
    for (int i = 0; i < 32; i += 8)
        tile[ty + i][tx] = src[(size_t)(k0 + ty + i) * HDIM + n0 + tx];
    __syncthreads();
#pragma unroll
    for (int i = 0; i < 32; i += 8)
        dst[(size_t)(n0 + ty + i) * K + k0 + tx] = (bf16)tile[tx][ty + i];
}

// ---------------------------------------------------------------------------
// K0b: x fp32 -> bf16
// ---------------------------------------------------------------------------
__global__ __launch_bounds__(256) void convert_x(const float* __restrict__ x, bf16* __restrict__ xbf) {
    size_t i = ((size_t)blockIdx.x * blockDim.x + threadIdx.x) * 4;
    float4 v = *(const float4*)(x + i);
    bf16x4 o = { (bf16)v.x, (bf16)v.y, (bf16)v.z, (bf16)v.w };
    *(bf16x4*)(xbf + i) = o;
}

// ---------------------------------------------------------------------------
// K0c: init h state (bf16) + zero barrier counters
// ---------------------------------------------------------------------------
__global__ __launch_bounds__(256) void init_h(const float* __restrict__ hf, const float* __restrict__ hb,
                                              bf16* __restrict__ h_cur, unsigned* __restrict__ bars) {
    int i = blockIdx.x * blockDim.x + threadIdx.x;
    h_cur[i] = (bf16)hf[i];
    h_cur[BATCH * HDIM + i] = (bf16)hb[i];
    if (blockIdx.x == 0) bars[threadIdx.x] = 0u;   // 256 u32 covers all 4 group counters
}

// ---------------------------------------------------------------------------
// K1: xproj GEMM. XP[g][t][b][n] = (x @ W_x_g)[b*T+t][n] + bias_g[n], bf16.
// ---------------------------------------------------------------------------
__global__ __launch_bounds__(256) void xproj_gemm(const bf16* __restrict__ xbf,
                                                  const bf16* __restrict__ wt_x,
                                                  Ptr6 biases,
                                                  bf16* __restrict__ XP) {
    int g  = blockIdx.z;
    int m0 = blockIdx.x * 64;
    int n0 = blockIdx.y * 64;
    int w  = threadIdx.x >> 6;
    int l  = threadIdx.x & 63;
    int lm = l & 15, lq = l >> 4;

    const bf16* Wg    = wt_x + (size_t)g * HDIM * IDIM;
    const bf16* Abase = xbf + (size_t)(m0 + 16 * w + lm) * IDIM + lq * 8;
    const bf16* Bbase = Wg + (size_t)(n0 + lm) * IDIM + lq * 8;

    f32x4 acc[4] = {};
#pragma unroll 2
    for (int k = 0; k < IDIM; k += 32) {
        bf16x8 a = *(const bf16x8*)(Abase + k);
#pragma unroll
        for (int nt = 0; nt < 4; nt++) {
            bf16x8 b = *(const bf16x8*)(Bbase + (size_t)nt * 16 * IDIM + k);
            acc[nt] = __builtin_amdgcn_mfma_f32_16x16x32_bf16(a, b, acc[nt], 0, 0, 0);
        }
    }

    const float* bias = biases.p[g];
    int mrow = m0 + 16 * w + lq * 4;
#pragma unroll
    for (int nt = 0; nt < 4; nt++) {
        int n = n0 + nt * 16 + lm;
        float bv = bias[n];
#pragma unroll
        for (int r = 0; r < 4; r++) {
            int m = mrow + r;
            int b_ = m >> 9;
            int t  = m & 511;
            XP[(((size_t)g * T_LEN + t) * BATCH + b_) * HDIM + n] = (bf16)(acc[nt][r] + bv);
        }
    }
}

// ---------------------------------------------------------------------------
// Group barrier over 64 blocks (one (dir,gb) group). RELAXED spin (no
// per-poll cache invalidation!); exactly one agent release fence before the
// arrive and one agent acquire fence after the spin exits.
// ---------------------------------------------------------------------------
__device__ inline void group_barrier(unsigned* ctr, unsigned target) {
    __syncthreads();
    if (threadIdx.x == 0) {
        __builtin_amdgcn_fence(__ATOMIC_RELEASE, "agent");
        __hip_atomic_fetch_add(ctr, 1u, __ATOMIC_RELAXED, __HIP_MEMORY_SCOPE_AGENT);
        while (__hip_atomic_load(ctr, __ATOMIC_RELAXED, __HIP_MEMORY_SCOPE_AGENT) < target) {
            __builtin_amdgcn_s_sleep(1);
        }
        __builtin_amdgcn_fence(__ATOMIC_ACQUIRE, "agent");
    }
    __syncthreads();
}

// ---------------------------------------------------------------------------
// K2: persistent recurrence kernel (cooperative launch, 256 blocks x 256 thr).
// block = (dir, gb batch-half, s 16-col slice). Weights for the block's 16
// columns (3 gates x K=1024 = 96 KB) pinned in LDS for all 512 steps.
// XP addends are register-prefetched BEFORE each barrier (XP is read-only,
// registers survive the acquire invalidate).
// ---------------------------------------------------------------------------
__global__ __launch_bounds__(256, 1) void gru_persistent(
        const bf16* __restrict__ wt_h, const bf16* __restrict__ XP,
        bf16* __restrict__ h_cur, bf16* __restrict__ Rh,
        float* __restrict__ out, unsigned* __restrict__ bars)
{
    __shared__ __align__(16) char  Wl[98304];   // 3 gates x 32768 B
    __shared__ __align__(16) float Part[512];   // phase-B cross-wave partials
    __shared__ __align__(16) float Zs[512];     // Z gate, phase A -> phase B

    const int blk = blockIdx.x;
    const int dir = blk >> 7;
    const int gb  = (blk >> 6) & 1;
    const int s   = blk & 63;
    const int n0  = s * 16;
    const int tid = threadIdx.x;
    const int w   = tid >> 6, l = tid & 63;
    const int lm  = l & 15, lq = l >> 4;

    // ---- preload this block's weight slices into LDS
    for (int gate = 0; gate < 3; ++gate) {
        const bf16* Wg = wt_h + ((size_t)(dir * 3 + gate) * HDIM + n0) * HDIM;
        char* dst = Wl + gate * 32768;
        for (int idx = tid; idx < 2048; idx += 256) {
            int c = idx & 15, kb = idx >> 4;           // col, 16B-chunk index
            bf16x8 v = *(const bf16x8*)(Wg + (size_t)c * HDIM + kb * 8);
            *(bf16x8*)(dst + kb * 256 + c * 16) = v;   // contiguous LDS write per 16 lanes
        }
    }
    __syncthreads();

    bf16* h_d  = h_cur + (size_t)dir * BATCH * HDIM;
    bf16* Rh_d = Rh    + (size_t)dir * BATCH * HDIM;
    unsigned* ctr = bars + (dir * 2 + gb) * 64;        // 256B-spaced counters

    const int gate = w >> 1;                 // phase A: 0=R, 1=Z
    const int mt   = w & 1;                  // row tile (both phases)
    const int kh   = w >> 1;                 // phase B: K-half
    const int rowA = gb * 32 + mt * 16 + lm; // A-fragment row
    const int brow = gb * 32 + mt * 16 + lq * 4;
    const int n    = n0 + lm;

    const char* BlA = Wl + gate * 32768 + lq * 256 + lm * 16;
    const char* BlB = Wl + 2 * 32768 + kh * 16384 + lq * 256 + lm * 16;

    unsigned bt = 0;

    // initial phase-A XP prefetch (step 0)
    float xpv[4];
    {
        const int t0 = dir ? (T_LEN - 1) : 0;
        const bf16* xpA = XP + ((size_t)(dir * 3 + gate) * T_LEN + t0) * BATCH * HDIM;
#pragma unroll
        for (int r = 0; r < 4; ++r)
            xpv[r] = (float)xpA[(size_t)(brow + r) * HDIM + n];
    }

#pragma unroll 1
    for (int step = 0; step < T_LEN; ++step) {
        const int t = dir ? (T_LEN - 1 - step) : step;

        // ======================= phase A: R / Z =======================
        {
            const bf16* A = h_d + (size_t)rowA * HDIM + lq * 8;
            float hvv[4] = {};
            if (gate == 0) {
#pragma unroll
                for (int r = 0; r < 4; ++r)
                    hvv[r] = (float)h_d[(size_t)(brow + r) * HDIM + n];
            }
            bf16x8 a[32];
#pragma unroll
            for (int i = 0; i < 32; ++i)
                a[i] = *(const bf16x8*)(A + i * 32);
            f32x4 acc0 = {}, acc1 = {};
#pragma unroll
            for (int i = 0; i < 32; i += 2) {
                bf16x8 b0 = *(const bf16x8*)(BlA + i * 1024);
                acc0 = __builtin_amdgcn_mfma_f32_16x16x32_bf16(a[i], b0, acc0, 0, 0, 0);
                bf16x8 b1 = *(const bf16x8*)(BlA + i * 1024 + 1024);
                acc1 = __builtin_amdgcn_mfma_f32_16x16x32_bf16(a[i + 1], b1, acc1, 0, 0, 0);
            }
            f32x4 acc = acc0 + acc1;
#pragma unroll
            for (int r = 0; r < 4; ++r) {
                float pre = acc[r] + xpv[r];
                float gv = 1.0f / (1.0f + __expf(-pre));
                if (gate == 0) {
                    Rh_d[(size_t)(brow + r) * HDIM + n] = (bf16)(gv * hvv[r]);
                } else {
                    Zs[mt * 256 + l * 4 + r] = gv;
                }
            }
        }
        // prefetch phase-B XP addend for this step into registers
        float xph[4];
        {
            const bf16* xpH = XP + ((size_t)(dir * 3 + 2) * T_LEN + t) * BATCH * HDIM;
#pragma unroll
            for (int r = 0; r < 4; ++r)
                xph[r] = (float)xpH[(size_t)(brow + r) * HDIM + n];
        }
        bt += 64; group_barrier(ctr, bt);

        // =================== phase B: h_til & update ===================
        {
            const bf16* A = Rh_d + (size_t)rowA * HDIM + kh * 512 + lq * 8;
            bf16x8 a[16];
#pragma unroll
            for (int i = 0; i < 16; ++i)
                a[i] = *(const bf16x8*)(A + i * 32);
            f32x4 acc0 = {}, acc1 = {};
#pragma unroll
            for (int i = 0; i < 16; i += 2) {
                bf16x8 b0 = *(const bf16x8*)(BlB + i * 1024);
                acc0 = __builtin_amdgcn_mfma_f32_16x16x32_bf16(a[i], b0, acc0, 0, 0, 0);
                bf16x8 b1 = *(const bf16x8*)(BlB + i * 1024 + 1024);
                acc1 = __builtin_amdgcn_mfma_f32_16x16x32_bf16(a[i + 1], b1, acc1, 0, 0, 0);
            }
            f32x4 p = acc0 + acc1;
            if (kh == 1)
                *(f32x4*)(&Part[mt * 256 + l * 4]) = p;
            __syncthreads();
            if (kh == 0) {
                f32x4 q = *(const f32x4*)(&Part[mt * 256 + l * 4]);
#pragma unroll
                for (int r = 0; r < 4; ++r) {
                    int b_ = brow + r;
                    float pre = p[r] + q[r] + xph[r];
                    float e2x = __expf(2.0f * pre);
                    float ht  = (e2x - 1.0f) / (e2x + 1.0f);
                    float z   = Zs[mt * 256 + l * 4 + r];
                    float ho  = (float)h_d[(size_t)b_ * HDIM + n];
                    float hn  = z * ht + (1.0f - z) * ho;
                    h_d[(size_t)b_ * HDIM + n] = (bf16)hn;
                    out[((size_t)b_ * T_LEN + t) * (2 * HDIM) + (size_t)dir * HDIM + n] = hn;
                }
            }
        }
        // prefetch phase-A XP addend for next step into registers
        {
            const int step2 = (step + 1 < T_LEN) ? step + 1 : step;
            const int t2 = dir ? (T_LEN - 1 - step2) : step2;
            const bf16* xpA = XP + ((size_t)(dir * 3 + gate) * T_LEN + t2) * BATCH * HDIM;
#pragma unroll
            for (int r = 0; r < 4; ++r)
                xpv[r] = (float)xpA[(size_t)(brow + r) * HDIM + n];
        }
        bt += 64; group_barrier(ctr, bt);
    }
}

// ---------------------------------------------------------------------------
extern "C" void kernel_launch(void* const* d_in, const int* in_sizes, int n_in,
                              void* d_out, int out_size, void* d_ws, size_t ws_size,
                              hipStream_t stream) {
    const float* x   = (const float*)d_in[0];
    const float* hpf = (const float*)d_in[1];
    const float* hpb = (const float*)d_in[2];

    unsigned char* ws = (unsigned char*)d_ws;
    size_t off = 0;
    bf16* wt_h = (bf16*)(ws + off); off += (size_t)6 * HDIM * HDIM * 2;
    bf16* wt_x = (bf16*)(ws + off); off += (size_t)6 * HDIM * IDIM * 2;
    bf16* xbf  = (bf16*)(ws + off); off += (size_t)BATCH * T_LEN * IDIM * 2;
    bf16* XP   = (bf16*)(ws + off); off += (size_t)6 * T_LEN * BATCH * HDIM * 2;
    bf16* h_cur = (bf16*)(ws + off); off += (size_t)2 * BATCH * HDIM * 2;
    bf16* Rh    = (bf16*)(ws + off); off += (size_t)2 * BATCH * HDIM * 2;
    unsigned* bars = (unsigned*)(ws + off); off += 1024;   // 4 counters, 256B apart

    float* out = (float*)d_out;

    Ptr12 wp;
    wp.p[0] = (const float*)d_in[3];  wp.p[1] = (const float*)d_in[6];  wp.p[2] = (const float*)d_in[9];
    wp.p[3] = (const float*)d_in[12]; wp.p[4] = (const float*)d_in[15]; wp.p[5] = (const float*)d_in[18];
    wp.p[6] = (const float*)d_in[4];  wp.p[7] = (const float*)d_in[7];  wp.p[8] = (const float*)d_in[10];
    wp.p[9] = (const float*)d_in[13]; wp.p[10] = (const float*)d_in[16]; wp.p[11] = (const float*)d_in[19];
    transpose_convert<<<dim3(32, 32, 12), 256, 0, stream>>>(wp, wt_h, wt_x);

    convert_x<<<16384, 256, 0, stream>>>(x, xbf);
    init_h<<<256, 256, 0, stream>>>(hpf, hpb, h_cur, bars);

    Ptr6 bp;
    bp.p[0] = (const float*)d_in[5];  bp.p[1] = (const float*)d_in[8];  bp.p[2] = (const float*)d_in[11];
    bp.p[3] = (const float*)d_in[14]; bp.p[4] = (const float*)d_in[17]; bp.p[5] = (const float*)d_in[20];
    xproj_gemm<<<dim3(512, 16, 6), 256, 0, stream>>>(xbf, wt_x, bp, XP);

    // Persistent recurrence: one cooperative kernel, 512 steps inside.
    void* args[] = { (void*)&wt_h, (void*)&XP, (void*)&h_cur, (void*)&Rh,
                     (void*)&out, (void*)&bars };
    (void)hipLaunchCooperativeKernel((void*)gru_persistent, dim3(256), dim3(256), args, 0, stream);
}